// Round 15
// baseline (712.568 us; speedup 1.0000x reference)
//
#include <hip/hip_runtime.h>
#include <cmath>

// Problem dims (fixed by setup_inputs)
#define B_SZ  32
#define LATD  64
#define HU    96
#define G4    384
#define T_LEN 512
#define VOC   10000
#define NROWS (B_SZ * T_LEN)        // 16384
#define NC16  625                   // 10000/16 exactly
#define NSPLIT 5
#define C16S  125                   // c16 tiles per split
#define RBLK  32                    // rows per dense block
#define PPR   (NSPLIT * 2)          // partials per row
#define HIST  64                    // LDS h-history ring depth
#define NLSTM (B_SZ / 2)            // 16 blocks, 2 batches each
#define PACK_BLOCKS ((NC16 * 3 * 64 + 383) / 384)   // 313
#define LSTM_GRID   (NLSTM + PACK_BLOCKS)           // 329

typedef __attribute__((ext_vector_type(8))) short bf16x8;
typedef __attribute__((ext_vector_type(4))) float f32x4;

__device__ __forceinline__ unsigned short f2bf(float x) {
  unsigned u = __float_as_uint(x);
  u += 0x7fffu + ((u >> 16) & 1u);   // RNE
  return (unsigned short)(u >> 16);
}
__device__ __forceinline__ float fsig(float x) {
  return __builtin_amdgcn_rcpf(1.f + __expf(-x));
}
__device__ __forceinline__ float ftanh(float x) {
  return 1.f - 2.f * __builtin_amdgcn_rcpf(1.f + __expf(2.f * x));
}

// ---------------- Kernel 1 (fused): 2-batch interleaved LSTM + Wd packing ---
// Blocks [0,16): LSTM, TWO batch elements each (2bb, 2bb+1), 6 waves.
//   Proven replicated-A MFMA body (R5-R8): wave w owns tiles {w,6+w,12+w,18+w}
//   = gates i,f,cb,o of unit u0 = c + 16w -> gate quad in-lane. The two
//   batches' independent per-step chains are interleaved in one body so
//   batch B's MFMA issue fills batch A's MFMA->VALU + trans-op latency and
//   vice versa (stall-sharing). Ufr registers shared (same U). Separate
//   64-step LDS rings, one barrier per step, bulk dump every 64 steps.
// Blocks [16, 329): pack Wd into bf16 MFMA-fragment order (other CUs).
__global__ __launch_bounds__(384) void lstm_fused2(
    const float* __restrict__ z, const float* __restrict__ W,
    const float* __restrict__ U, const float* __restrict__ bias,
    const float* __restrict__ Wd, unsigned short* __restrict__ hsb,
    uint4* __restrict__ Bp) {
  const int tid = threadIdx.x;

  if (blockIdx.x >= NLSTM) {
    // ---- pack path: chunk (c16,K16,l): elem j = Wd[K16*32+(l>>4)*8+j][c16*16+(l&15)]
    const int gid = (blockIdx.x - NLSTM) * 384 + tid;
    if (gid < NC16 * 3 * 64) {
      const int l   = gid & 63;
      const int K16 = (gid >> 6) % 3;
      const int c16 = gid / 192;
      const int col = c16 * 16 + (l & 15);
      const int k0  = K16 * 32 + (l >> 4) * 8;
      unsigned wb[4];
#pragma unroll
      for (int jj = 0; jj < 4; ++jj) {
        float x0 = Wd[(size_t)(k0 + 2 * jj) * VOC + col];
        float x1 = Wd[(size_t)(k0 + 2 * jj + 1) * VOC + col];
        wb[jj] = (unsigned)f2bf(x0) | ((unsigned)f2bf(x1) << 16);
      }
      Bp[gid] = make_uint4(wb[0], wb[1], wb[2], wb[3]);
    }
    return;
  }

  // ---- LSTM path: batches bA = 2*bb, bB = 2*bb+1 ----
  __shared__ __align__(16) unsigned short ringA[HIST][HU];  // 12 KB
  __shared__ __align__(16) unsigned short ringB[HIST][HU];  // 12 KB
  __shared__ float z_lds[2][LATD];
  const int bb = blockIdx.x;
  const int l  = tid & 63, wv = tid >> 6;   // wave 0..5
  const int c  = l & 15, kg = l >> 4, k0 = kg * 8;

  if (tid < 2 * LATD) ((float*)z_lds)[tid] = z[bb * 2 * LATD + tid];
  if (tid < 12) {
    ((uint4*)(ringA[HIST - 1]))[tid] = make_uint4(0u, 0u, 0u, 0u);
    ((uint4*)(ringB[HIST - 1]))[tid] = make_uint4(0u, 0u, 0u, 0u);
  }

  // this lane's 4 gate columns: gate g of unit (c + 16*wv) = col (6g+wv)*16+c
  int cols[4];
#pragma unroll
  for (int g = 0; g < 4; ++g) cols[g] = (6 * g + wv) * 16 + c;

  // U fragments (MFMA B-operand layout): 48 VGPRs, shared by both batches
  bf16x8 Ufr[4][3];
#pragma unroll
  for (int g = 0; g < 4; ++g) {
#pragma unroll
    for (int kt = 0; kt < 3; ++kt) {
      const int kb = kt * 32 + k0;
      unsigned wb[4];
#pragma unroll
      for (int jj = 0; jj < 4; ++jj) {
        float x0 = U[(size_t)(kb + 2 * jj) * G4 + cols[g]];
        float x1 = U[(size_t)(kb + 2 * jj + 1) * G4 + cols[g]];
        wb[jj] = (unsigned)f2bf(x0) | ((unsigned)f2bf(x1) << 16);
      }
      uint4 u4 = make_uint4(wb[0], wb[1], wb[2], wb[3]);
      Ufr[g][kt] = __builtin_bit_cast(bf16x8, u4);
    }
  }

  float zpA[4], zpB[4];
#pragma unroll
  for (int g = 0; g < 4; ++g) { zpA[g] = bias[cols[g]]; zpB[g] = zpA[g]; }
  __syncthreads();  // z_lds + ring init visible
  for (int k = 0; k < LATD; ++k) {
    const float zkA = z_lds[0][k], zkB = z_lds[1][k];
    const float* wr = W + (size_t)k * G4;
#pragma unroll
    for (int g = 0; g < 4; ++g) {
      const float w_ = wr[cols[g]];
      zpA[g] = fmaf(zkA, w_, zpA[g]);
      zpB[g] = fmaf(zkB, w_, zpB[g]);
    }
  }

  float cstA = 0.f, cstB = 0.f;
  unsigned short* hrowA = hsb + (size_t)(2 * bb) * T_LEN * HU;
  unsigned short* hrowB = hsb + (size_t)(2 * bb + 1) * T_LEN * HU;
  const f32x4 zero4 = {0.f, 0.f, 0.f, 0.f};
  const int u0 = c + 16 * wv;

  for (int s = 0; s < T_LEN; ++s) {
    const int rs = (s + HIST - 1) & (HIST - 1);
    bf16x8 afrA[3], afrB[3];
#pragma unroll
    for (int kt = 0; kt < 3; ++kt) {
      afrA[kt] = *(const bf16x8*)(&ringA[rs][kt * 32 + k0]);
      afrB[kt] = *(const bf16x8*)(&ringB[rs][kt * 32 + k0]);
    }

    // issue both batches' MFMAs back-to-back (independent dataflow)
    float gA[4], gB[4];
#pragma unroll
    for (int g = 0; g < 4; ++g) {
      f32x4 da = __builtin_amdgcn_mfma_f32_16x16x32_bf16(afrA[0], Ufr[g][0], zero4, 0, 0, 0);
      da = __builtin_amdgcn_mfma_f32_16x16x32_bf16(afrA[2], Ufr[g][2], da, 0, 0, 0);
      f32x4 db = __builtin_amdgcn_mfma_f32_16x16x32_bf16(afrA[1], Ufr[g][1], zero4, 0, 0, 0);
      gA[g] = (da[0] + db[0]) + zpA[g];
    }
#pragma unroll
    for (int g = 0; g < 4; ++g) {
      f32x4 da = __builtin_amdgcn_mfma_f32_16x16x32_bf16(afrB[0], Ufr[g][0], zero4, 0, 0, 0);
      da = __builtin_amdgcn_mfma_f32_16x16x32_bf16(afrB[2], Ufr[g][2], da, 0, 0, 0);
      f32x4 db = __builtin_amdgcn_mfma_f32_16x16x32_bf16(afrB[1], Ufr[g][1], zero4, 0, 0, 0);
      gB[g] = (da[0] + db[0]) + zpB[g];
    }

    // batch A activations (B's MFMAs still in flight underneath)
    {
      const float i_ = fsig(gA[0]);
      const float f_ = fsig(gA[1]);
      const float cb = ftanh(gA[2]);
      const float o_ = fsig(gA[3]);
      cstA = f_ * cstA + i_ * cb;
      const float h = o_ * ftanh(cstA);
      if (kg == 0) ringA[s & (HIST - 1)][u0] = f2bf(h);
    }
    // batch B activations
    {
      const float i_ = fsig(gB[0]);
      const float f_ = fsig(gB[1]);
      const float cb = ftanh(gB[2]);
      const float o_ = fsig(gB[3]);
      cstB = f_ * cstB + i_ * cb;
      const float h = o_ * ftanh(cstB);
      if (kg == 0) ringB[s & (HIST - 1)][u0] = f2bf(h);
    }
    __syncthreads();

    if ((s & (HIST - 1)) == (HIST - 1)) {
      // bulk dump both rings (steps s-63..s), coalesced
      const int s0 = s - (HIST - 1);
      const uint4* srcA = (const uint4*)ringA;
      const uint4* srcB = (const uint4*)ringB;
      uint4* dstA = (uint4*)(hrowA + (size_t)s0 * HU);
      uint4* dstB = (uint4*)(hrowB + (size_t)s0 * HU);
      for (int i = tid; i < HIST * HU / 8; i += 384) {
        dstA[i] = srcA[i];
        dstB[i] = srcB[i];
      }
      __syncthreads();  // rings reusable only after all dump reads done
    }
  }
}

// ---------------- Kernels 2/4: dense GEMM passes (R5-proven, unchanged) -----
// Grid: 512 row-blocks x NSPLIT v-splits (bid: s=bid/512, rb=bid%512).
// 4 waves: r16 = wv&1 (16-row tile), cg = wv>>1 (odd/even c16 within split).
// PASS 0: partial sum(exp(logit)) -> part[row][s*2+cg].
// PASS 1: recompute logits (identical MFMA sequence) -> nontemporal out.
template <int PASS>
__global__ __launch_bounds__(256) void dense_pass(
    const unsigned short* __restrict__ hsb, const bf16x8* __restrict__ Bp,
    const float* __restrict__ bd, const float* __restrict__ invS,
    float* __restrict__ outp) {
  __shared__ __align__(16) unsigned short Al[RBLK * HU];  // 6 KB
  const int tid = threadIdx.x;
  const int l = tid & 63, wv = tid >> 6;
  const int r16 = wv & 1, cg = wv >> 1;
  const int l15 = l & 15, l4 = l >> 4;
  const int s = blockIdx.x / 512, rb = blockIdx.x % 512;
  const int R0 = rb * RBLK;

  {
    const uint4* src = (const uint4*)(hsb + (size_t)R0 * HU);
    uint4* dst = (uint4*)Al;
    for (int i = tid; i < RBLK * HU / 8; i += 256) dst[i] = src[i];
  }
  __syncthreads();

  bf16x8 afr[3];
#pragma unroll
  for (int K16 = 0; K16 < 3; ++K16)
    afr[K16] = *(const bf16x8*)(Al + (r16 * 16 + l15) * HU + K16 * 32 + l4 * 8);

  float iv[4];
  float ssum[4] = {0.f, 0.f, 0.f, 0.f};
  if (PASS == 1) {
#pragma unroll
    for (int q = 0; q < 4; ++q) iv[q] = invS[R0 + r16 * 16 + l4 * 4 + q];
  }

  const int cbase = s * C16S;
  for (int i = cg; i < C16S; i += 2) {
    const int c16 = cbase + i;
    const bf16x8* bp = Bp + (size_t)c16 * 192 + l;
    const bf16x8 b0 = bp[0], b1 = bp[64], b2 = bp[128];
    f32x4 acc = {0.f, 0.f, 0.f, 0.f};
    acc = __builtin_amdgcn_mfma_f32_16x16x32_bf16(afr[0], b0, acc, 0, 0, 0);
    acc = __builtin_amdgcn_mfma_f32_16x16x32_bf16(afr[1], b1, acc, 0, 0, 0);
    acc = __builtin_amdgcn_mfma_f32_16x16x32_bf16(afr[2], b2, acc, 0, 0, 0);
    const int col = c16 * 16 + l15;
    const float bdv = bd[col];
    if (PASS == 0) {
#pragma unroll
      for (int q = 0; q < 4; ++q) ssum[q] += __expf(acc[q] + bdv);
    } else {
#pragma unroll
      for (int q = 0; q < 4; ++q) {
        const size_t r = (size_t)(R0 + r16 * 16 + l4 * 4 + q);
        __builtin_nontemporal_store(__expf(acc[q] + bdv) * iv[q],
                                    outp + r * VOC + col);
      }
    }
  }

  if (PASS == 0) {
#pragma unroll
    for (int q = 0; q < 4; ++q) {
      float v = ssum[q];
      v += __shfl_xor(v, 1);
      v += __shfl_xor(v, 2);
      v += __shfl_xor(v, 4);
      v += __shfl_xor(v, 8);
      ssum[q] = v;
    }
    if (l15 == 0) {
#pragma unroll
      for (int q = 0; q < 4; ++q)
        outp[(size_t)(R0 + r16 * 16 + l4 * 4 + q) * PPR + s * 2 + cg] = ssum[q];
    }
  }
}

// ---------------- Kernel 3: reduce partials -> invS (R5-proven) -------------
__global__ __launch_bounds__(256) void reduce_inv(const float* __restrict__ part,
                                                  float* __restrict__ invS) {
  const int r = blockIdx.x * 256 + threadIdx.x;
  if (r < NROWS) {
    float s = 0.f;
#pragma unroll
    for (int i = 0; i < PPR; ++i) s += part[(size_t)r * PPR + i];
    invS[r] = 1.f / s;
  }
}

extern "C" void kernel_launch(void* const* d_in, const int* in_sizes, int n_in,
                              void* d_out, int out_size, void* d_ws, size_t ws_size,
                              hipStream_t stream) {
  const float* z  = (const float*)d_in[0];
  const float* W  = (const float*)d_in[1];
  const float* U  = (const float*)d_in[2];
  const float* b  = (const float*)d_in[3];
  const float* Wd = (const float*)d_in[4];
  const float* bd = (const float*)d_in[5];
  float* out = (float*)d_out;

  char* ws = (char*)d_ws;
  unsigned short* hsb = (unsigned short*)ws;                 // 3,145,728 B
  uint4* Bp   = (uint4*)(ws + 3145728);                      // 1,920,000 B
  float* part = (float*)(ws + 3145728 + 1920000);            //   655,360 B
  float* invS = (float*)(ws + 3145728 + 1920000 + 655360);   //    65,536 B

  lstm_fused2<<<LSTM_GRID, 384, 0, stream>>>(z, W, U, b, Wd, hsb, Bp);
  dense_pass<0><<<512 * NSPLIT, 256, 0, stream>>>(hsb, (const bf16x8*)Bp, bd,
                                                  nullptr, part);
  reduce_inv<<<(NROWS + 255) / 256, 256, 0, stream>>>(part, invS);
  dense_pass<1><<<512 * NSPLIT, 256, 0, stream>>>(hsb, (const bf16x8*)Bp, bd,
                                                  invS, out);
}